// Round 8
// baseline (72.987 us; speedup 1.0000x reference)
//
#include <hip/hip_runtime.h>

// CPAMDec — R8: full MFMA pipeline + per-lane softmax + vectorized LDS-staged epilogue.
//   energy[px][kk] = sum_c x_bf[px][c] * wqk_bf[c][kk] (+bqk)  [A from global, B=wqkf frags]
//   out[c][px]     = fs * sum_kk vT_bf[c][kk] * attn_bf[kk][px] + x[c][px]
// Frag layouts (mfma_f32_16x16x32_bf16), HW-verified R5/R6:
//   A[m][k]: lane l -> m=l&15, k=8*(l>>4)+j ; B[k][n]: lane l -> n=l&15, k=8*(l>>4)+j
//   D[m][n]: lane l -> n=l&15, m=4*(l>>4)+r
// ws: wqkf bf16[N][32*512] @0 | vtf bf16[N][32*512] @256K | bqk f32[256] @512K | vp f32[2][N*32*512] @525312

#define N_  8
#define C_  512
#define HW_ 4096
#define K_  32

typedef __attribute__((ext_vector_type(8))) short bf16x8;
typedef __attribute__((ext_vector_type(4))) float f32x4;
typedef __attribute__((ext_vector_type(4))) int i32x4;

__device__ __forceinline__ unsigned short f2b(float f) {
    union { float f; unsigned u; } v; v.f = f;
    unsigned r = v.u + 0x7FFFu + ((v.u >> 16) & 1u);   // RNE
    return (unsigned short)(r >> 16);
}

// wqk frag slot: wqk[kk][c] -> elem ((cs*2+kt)*64 + g*16 + (kk&15))*8 + j
__device__ __forceinline__ int wqk_idx(int kk, int c) {
    return ((((c >> 5) * 2 + (kk >> 4)) * 64 + ((c >> 3) & 3) * 16 + (kk & 15)) << 3) + (c & 7);
}

__global__ __launch_bounds__(256) void prep_kernel(
    const float* __restrict__ y, const float* __restrict__ wq, const float* __restrict__ bq,
    const float* __restrict__ wk, const float* __restrict__ bk,
    const float* __restrict__ wv, const float* __restrict__ bv,
    unsigned short* __restrict__ wqkf, float* __restrict__ bqk, float* __restrict__ vp)
{
    const int bid = blockIdx.x;
    const int t = threadIdx.x;

    if (bid < 256) {
        // role A: v partials. block = (n, ct of 32 c, j-half). thread = (cl, ko -> 4 kk)
        const int n  = bid >> 5;
        const int ct = (bid >> 1) & 15;
        const int jh = bid & 1;
        const int cl = t & 31;
        const int c  = ct * 32 + cl;
        const int ko = t >> 5;                          // 0..7

        const float* yb  = y  + ((size_t)n * K_ + ko * 4) * C_ + jh * 256;
        const float* wvb = wv + (size_t)c * C_ + jh * 256;
        float acc[4] = {0.f, 0.f, 0.f, 0.f};
        #pragma unroll 4
        for (int jq = 0; jq < 64; ++jq) {
            float4 w4 = *(const float4*)(wvb + jq * 4);
            #pragma unroll
            for (int u = 0; u < 4; ++u) {
                float4 y4 = *(const float4*)(yb + (size_t)u * C_ + jq * 4);
                acc[u] += y4.x * w4.x + y4.y * w4.y + y4.z * w4.z + y4.w * w4.w;
            }
        }
        const float bvc = (jh == 0) ? bv[c] : 0.0f;
        float* vpo = vp + (size_t)jh * N_ * K_ * C_;
        #pragma unroll
        for (int u = 0; u < 4; ++u)
            vpo[((size_t)n * K_ + ko * 4 + u) * C_ + c] = acc[u] + bvc;
    } else {
        // role B: krow -> bqk, wqk frags. block = (n, kk)
        __shared__ __align__(16) float kp[2][128];
        __shared__ __align__(16) float kr[128];
        const int b = bid - 256;
        const int n = b >> 5, kk = b & 31;
        const int o = t & 127, half = t >> 7;

        const float* yb  = y  + ((size_t)n * K_ + kk) * C_ + half * 256;
        const float* wkb = wk + (size_t)o * C_ + half * 256;
        float a = 0.f;
        #pragma unroll 4
        for (int jq = 0; jq < 64; ++jq) {
            float4 w4 = *(const float4*)(wkb + jq * 4);
            float4 y4 = *(const float4*)(yb + jq * 4);
            a += y4.x * w4.x + y4.y * w4.y + y4.z * w4.z + y4.w * w4.w;
        }
        kp[half][o] = a;
        __syncthreads();
        if (t < 128) kr[t] = kp[0][t] + kp[1][t] + bk[t];
        __syncthreads();
        if (t < 64) {
            float s = kr[t] * bq[t] + kr[t + 64] * bq[t + 64];
            #pragma unroll
            for (int d = 32; d > 0; d >>= 1) s += __shfl_down(s, d);
            if (t == 0) bqk[n * K_ + kk] = s;
        }
        const int c1 = t, c2 = t + 256;
        float s1 = 0.f, s2 = 0.f;
        for (int oq = 0; oq < 32; ++oq) {
            float4 k4 = *(const float4*)(&kr[oq * 4]);
            const float* wq0 = wq + (size_t)(oq * 4) * C_;
            s1 += k4.x * wq0[c1] + k4.y * wq0[C_ + c1] + k4.z * wq0[2*C_ + c1] + k4.w * wq0[3*C_ + c1];
            s2 += k4.x * wq0[c2] + k4.y * wq0[C_ + c2] + k4.z * wq0[2*C_ + c2] + k4.w * wq0[3*C_ + c2];
        }
        unsigned short* wqf_n = wqkf + (size_t)n * (K_ * C_);
        wqf_n[wqk_idx(kk, c1)] = f2b(s1);
        wqf_n[wqk_idx(kk, c2)] = f2b(s2);
    }
}

// vT A-frag: slot (mt*64 + l)*8 + j = v[kk=8*(l>>4)+j][c=mt*16+(l&15)]
__global__ __launch_bounds__(128) void pack_v_kernel(
    const float* __restrict__ vp, unsigned short* __restrict__ vtf)
{
    const int gid = blockIdx.x * 128 + threadIdx.x;     // 16384 slots
    const int n = gid >> 11, rem = gid & 2047;
    const int l = rem & 63;
    const int mt = rem >> 6;
    const int c = mt * 16 + (l & 15), g = l >> 4;
    const float* p0 = vp + ((size_t)n * K_ + g * 8) * C_ + c;
    const float* p1 = p0 + (size_t)N_ * K_ * C_;
    float s[8];
    #pragma unroll
    for (int j = 0; j < 8; ++j) s[j] = p0[(size_t)j * C_];
    #pragma unroll
    for (int j = 0; j < 8; ++j) s[j] += p1[(size_t)j * C_];
    unsigned short o[8];
    #pragma unroll
    for (int j = 0; j < 8; ++j) o[j] = f2b(s[j]);
    i32x4 pk = { (int)(o[0] | ((unsigned)o[1] << 16)), (int)(o[2] | ((unsigned)o[3] << 16)),
                 (int)(o[4] | ((unsigned)o[5] << 16)), (int)(o[6] | ((unsigned)o[7] << 16)) };
    *(i32x4*)(vtf + (size_t)n * (K_ * C_) + (size_t)rem * 8) = pk;
}

__global__ __launch_bounds__(512) void main_kernel(
    const float* __restrict__ x, const unsigned short* __restrict__ wqkf,
    const unsigned short* __restrict__ vtf, const float* __restrict__ bqk,
    const float* __restrict__ scale, float* __restrict__ out)
{
    __shared__ float e_lds[64][33];                        // 8.25 KB
    __shared__ __align__(16) float obuf[128][68];          // 34 KB epilogue staging

    const int bid = blockIdx.x;
    const int n  = bid >> 6;
    const int p0 = (bid & 63) * 64;
    const int t  = threadIdx.x;
    const int w  = t >> 6, l = t & 63;
    const int l15 = l & 15, lg = l >> 4;
    const float* xg = x + (size_t)n * C_ * HW_;
    float* og = out + (size_t)n * C_ * HW_;

    // ---- Phase 1: energy MFMA; A per-lane from global, depth-2 pipelined ----
    {
        const int pt = w & 3, kt = w >> 2;
        const unsigned short* wqf = wqkf + (size_t)n * (K_ * C_);
        const float* xc = xg + p0 + pt * 16 + l15;

        float xr0[8], xr1[8];
        #pragma unroll
        for (int u = 0; u < 8; ++u) xr0[u] = xc[(size_t)(8 * lg + u) * HW_];
        #pragma unroll
        for (int u = 0; u < 8; ++u) xr1[u] = xc[(size_t)(32 + 8 * lg + u) * HW_];
        bf16x8 b0 = *(const bf16x8*)(wqf + ((size_t)(0 + kt) * 64 + l) * 8);
        bf16x8 b1 = *(const bf16x8*)(wqf + ((size_t)(2 + kt) * 64 + l) * 8);

        f32x4 acc = {0.f, 0.f, 0.f, 0.f};
        for (int cs = 0; cs < 16; cs += 2) {
            float xn0[8], xn1[8];
            bf16x8 bn0, bn1;
            if (cs < 14) {
                #pragma unroll
                for (int u = 0; u < 8; ++u)
                    xn0[u] = xc[(size_t)((cs + 2) * 32 + 8 * lg + u) * HW_];
                bn0 = *(const bf16x8*)(wqf + ((size_t)((cs + 2) * 2 + kt) * 64 + l) * 8);
                #pragma unroll
                for (int u = 0; u < 8; ++u)
                    xn1[u] = xc[(size_t)((cs + 3) * 32 + 8 * lg + u) * HW_];
                bn1 = *(const bf16x8*)(wqf + ((size_t)((cs + 3) * 2 + kt) * 64 + l) * 8);
            }
            bf16x8 af0, af1;
            #pragma unroll
            for (int u = 0; u < 8; ++u) af0[u] = (short)f2b(xr0[u]);
            acc = __builtin_amdgcn_mfma_f32_16x16x32_bf16(af0, b0, acc, 0, 0, 0);
            #pragma unroll
            for (int u = 0; u < 8; ++u) af1[u] = (short)f2b(xr1[u]);
            acc = __builtin_amdgcn_mfma_f32_16x16x32_bf16(af1, b1, acc, 0, 0, 0);
            #pragma unroll
            for (int u = 0; u < 8; ++u) { xr0[u] = xn0[u]; xr1[u] = xn1[u]; }
            b0 = bn0; b1 = bn1;
        }
        const float bq_ = bqk[n * K_ + kt * 16 + l15];
        #pragma unroll
        for (int r = 0; r < 4; ++r)
            e_lds[pt * 16 + lg * 4 + r][kt * 16 + l15] = acc[r] + bq_;
    }
    __syncthreads();

    // ---- Phase 2: per-lane softmax for px = pt*16+l15; PV B-frag built in regs ----
    bf16x8 paf;
    {
        const int pt = w & 3;
        const float* er = e_lds[pt * 16 + l15];
        float e[32];
        #pragma unroll
        for (int k = 0; k < 32; ++k) e[k] = er[k];
        float mx = e[0];
        #pragma unroll
        for (int k = 1; k < 32; ++k) mx = fmaxf(mx, e[k]);
        float s = 0.f;
        #pragma unroll
        for (int k = 0; k < 32; ++k) { e[k] = __expf(e[k] - mx); s += e[k]; }
        const float inv = 1.f / s;
        #pragma unroll
        for (int j = 0; j < 8; ++j) paf[j] = (short)f2b(e[8 * lg + j] * inv);
    }

    // ---- Phase 3: PV MFMA -> obuf chunks -> vectorized residual+store ----
    {
        const int pt = w & 3, mh = w >> 2;
        const unsigned short* vtfn = vtf + (size_t)n * (K_ * C_);
        const float fs = scale[0];
        const int q = t & 15, r32 = t >> 4;             // epilogue mapping

        for (int ch = 0; ch < 4; ++ch) {
            // residual prefetch for this chunk (independent of barriers)
            float4 xres[4];
            int crow[4];
            #pragma unroll
            for (int rep = 0; rep < 4; ++rep) {
                const int row = rep * 32 + r32;
                const int c = (row < 64) ? (ch * 64 + row) : (256 + ch * 64 + (row - 64));
                crow[rep] = c;
                xres[rep] = *(const float4*)(xg + (size_t)c * HW_ + p0 + q * 4);
            }
            // 4 PV MFMAs for this chunk
            bf16x8 vf[4];
            #pragma unroll
            for (int mi = 0; mi < 4; ++mi) {
                const int mt = mh * 16 + ch * 4 + mi;
                vf[mi] = *(const bf16x8*)(vtfn + ((size_t)mt * 64 + l) * 8);
            }
            #pragma unroll
            for (int mi = 0; mi < 4; ++mi) {
                f32x4 d = __builtin_amdgcn_mfma_f32_16x16x32_bf16(vf[mi], paf, (f32x4){0.f,0.f,0.f,0.f}, 0, 0, 0);
                const int rbase = mh * 64 + mi * 16 + lg * 4;
                #pragma unroll
                for (int r = 0; r < 4; ++r)
                    obuf[rbase + r][pt * 16 + l15] = d[r];
            }
            __syncthreads();
            #pragma unroll
            for (int rep = 0; rep < 4; ++rep) {
                const int row = rep * 32 + r32;
                float4 dv = *(const float4*)&obuf[row][q * 4];
                float4 ov;
                ov.x = fs * dv.x + xres[rep].x;
                ov.y = fs * dv.y + xres[rep].y;
                ov.z = fs * dv.z + xres[rep].z;
                ov.w = fs * dv.w + xres[rep].w;
                *(float4*)(og + (size_t)crow[rep] * HW_ + p0 + q * 4) = ov;
            }
            __syncthreads();
        }
    }
}

extern "C" void kernel_launch(void* const* d_in, const int* in_sizes, int n_in,
                              void* d_out, int out_size, void* d_ws, size_t ws_size,
                              hipStream_t stream) {
    const float* x     = (const float*)d_in[0];
    const float* y     = (const float*)d_in[1];
    const float* wq    = (const float*)d_in[2];
    const float* bq    = (const float*)d_in[3];
    const float* wk    = (const float*)d_in[4];
    const float* bk    = (const float*)d_in[5];
    const float* wv    = (const float*)d_in[6];
    const float* bv    = (const float*)d_in[7];
    const float* scale = (const float*)d_in[8];

    unsigned short* wqkf = (unsigned short*)d_ws;                       // 256 KB
    unsigned short* vtf  = wqkf + (size_t)N_ * K_ * C_;                 // 256 KB
    float* bqk = (float*)((char*)d_ws + 524288);                        // 1 KB
    float* vp  = (float*)((char*)d_ws + 525312);                        // 1 MB (vp0|vp1)

    prep_kernel<<<512, 256, 0, stream>>>(y, wq, bq, wk, bk, wv, bv, wqkf, bqk, vp);
    pack_v_kernel<<<128, 128, 0, stream>>>(vp, vtf);
    main_kernel<<<N_ * 64, 512, 0, stream>>>(x, wqkf, vtf, bqk, scale, (float*)d_out);
}